// Round 5
// baseline (707.802 us; speedup 1.0000x reference)
//
#include <hip/hip_runtime.h>
#include <hip/hip_bf16.h>

// Problem constants (B=8, L=8192, C=256, PE=96, R=90, UP=4, OUT=256)
#define M_TOTAL 65536   // B*L
#define N_TOTAL 1024    // OUT*UP
#define K_TOTAL 448     // C + 2*PE
#define R_PE    90

typedef __bf16 bf16x8 __attribute__((ext_vector_type(8)));
typedef __bf16 bf16x4 __attribute__((ext_vector_type(4)));
typedef float  floatx4 __attribute__((ext_vector_type(4)));

// ---------------------------------------------------------------------------
// async global->LDS, 16B per lane. LDS dest = wave-uniform base + lane*16.
// ---------------------------------------------------------------------------
__device__ __forceinline__ void g2lds16(const void* g, void* l) {
    __builtin_amdgcn_global_load_lds(
        (const __attribute__((address_space(1))) void*)g,
        (__attribute__((address_space(3))) void*)l,
        16, 0, 0);
}

// ---------------------------------------------------------------------------
// cpe [3][96][90] -> cpeT [3][90][96] so per-lane d-gathers are contiguous.
// ---------------------------------------------------------------------------
__global__ __launch_bounds__(256) void transpose_cpe(
    const float* __restrict__ cpe, float* __restrict__ cpeT)
{
    int i = blockIdx.x * 256 + threadIdx.x;
    if (i < 3 * 96 * R_PE) {
        int c = i / (96 * R_PE);
        int rem = i % (96 * R_PE);
        int d = rem / R_PE;
        int r = rem % R_PE;
        cpeT[((size_t)c * R_PE + r) * 96 + d] = cpe[i];
    }
}

// ---------------------------------------------------------------------------
// sub_w [1024,448] f32 -> bf16 (already B^T layout: N-major, K-contiguous)
// ---------------------------------------------------------------------------
__global__ __launch_bounds__(256) void convert_w(
    const float* __restrict__ w, __bf16* __restrict__ wb)
{
    int i = (blockIdx.x * 256 + threadIdx.x) * 4;
    if (i < N_TOTAL * K_TOTAL) {
        float4 v = *(const float4*)(w + i);
        bf16x4 o = { (__bf16)v.x, (__bf16)v.y, (__bf16)v.z, (__bf16)v.w };
        *(bf16x4*)(wb + i) = o;
    }
}

// ---------------------------------------------------------------------------
// pc_up: repeat_interleave(pc, 4, axis=1)
// ---------------------------------------------------------------------------
__global__ __launch_bounds__(256) void pc_up_kernel(
    const float* __restrict__ pc, float* __restrict__ out2)
{
    int e = blockIdx.x * 256 + threadIdx.x;
    if (e < M_TOTAL * 12) {
        int m = e / 12;
        int j = e % 3;
        out2[e] = pc[m * 3 + j];
    }
}

// ---------------------------------------------------------------------------
// Per-lane PE fragment for MFMA A-operand: 8 bf16 values at
//   d = D8 + quad*8 + e   (D8 = (ktile-4)*64 + s*32, compile-time)
// D8 in {0,32,64}  -> sin(pc . lff_w[d] + lff_b[d])
// D8 in {96,128,160} -> bilinear const-PE at d0 = D8-96+quad*8, /sqrt(3)
// (96 % 32 == 0, so each fragment is branch-uniform at compile time.)
// ---------------------------------------------------------------------------
template<int D8>
__device__ __forceinline__ bf16x8 pe_frag(
    int quad, float p0, float p1, float p2,
    const float* __restrict__ lff_w, const float* __restrict__ lff_b,
    const float* __restrict__ cpeT)
{
    float val[8];
    if constexpr (D8 < 96) {
        const int db = D8 + quad * 8;
        const float* wp = lff_w + db * 3;
        const float* bp = lff_b + db;
        #pragma unroll
        for (int e = 0; e < 8; ++e) {
            float a = fmaf(p2, wp[e * 3 + 2],
                      fmaf(p1, wp[e * 3 + 1],
                      fmaf(p0, wp[e * 3 + 0], bp[e])));
            val[e] = __sinf(a);
        }
    } else {
        const int d0 = (D8 - 96) + quad * 8;      // 32B-aligned offset
        float a8[8] = {0.f,0.f,0.f,0.f,0.f,0.f,0.f,0.f};
        const float pch[3] = { p0, p1, p2 };
        #pragma unroll
        for (int c = 0; c < 3; ++c) {
            float ix = (pch[c] + 1.f) * 45.f - 0.5f;   // ((p+1)*R-1)*0.5
            float fl = floorf(ix);
            float w  = ix - fl;
            int   i0 = (int)fl;
            bool  ok0 = (i0 >= 0) && (i0 < R_PE);
            bool  ok1 = (i0 + 1 >= 0) && (i0 + 1 < R_PE);
            const float* t0 = cpeT + ((size_t)(c * R_PE + (ok0 ? i0     : 0))) * 96 + d0;
            const float* t1 = cpeT + ((size_t)(c * R_PE + (ok1 ? i0 + 1 : 0))) * 96 + d0;
            float w0 = ok0 ? (1.f - w) : 0.f;
            float w1 = ok1 ? w : 0.f;
            float4 u0 = *(const float4*)t0, u1 = *(const float4*)(t0 + 4);
            float4 v0 = *(const float4*)t1, v1 = *(const float4*)(t1 + 4);
            a8[0] = fmaf(w0, u0.x, fmaf(w1, v0.x, a8[0]));
            a8[1] = fmaf(w0, u0.y, fmaf(w1, v0.y, a8[1]));
            a8[2] = fmaf(w0, u0.z, fmaf(w1, v0.z, a8[2]));
            a8[3] = fmaf(w0, u0.w, fmaf(w1, v0.w, a8[3]));
            a8[4] = fmaf(w0, u1.x, fmaf(w1, v1.x, a8[4]));
            a8[5] = fmaf(w0, u1.y, fmaf(w1, v1.y, a8[5]));
            a8[6] = fmaf(w0, u1.z, fmaf(w1, v1.z, a8[6]));
            a8[7] = fmaf(w0, u1.w, fmaf(w1, v1.w, a8[7]));
        }
        #pragma unroll
        for (int e = 0; e < 8; ++e) val[e] = a8[e] * 0.57735026918962576f;
    }
    bf16x8 o = { (__bf16)val[0], (__bf16)val[1], (__bf16)val[2], (__bf16)val[3],
                 (__bf16)val[4], (__bf16)val[5], (__bf16)val[6], (__bf16)val[7] };
    return o;
}

// ---------------------------------------------------------------------------
// Streaming GEMM, barrier-free main loop.
//   Tile: M=256 x N=64, 512 threads (8 waves), wave w owns rows w*32..w*32+31.
//   B panel (64 n-rows x 448 k, bf16, XOR-swizzled) staged ONCE in LDS (56 KB)
//   -> single __syncthreads(); afterwards waves run fully independently:
//     K-tiles 0-3: A = bf16(X) from global f32, 1-tile register prefetch
//                  (compiler-tracked vmcnt; no DMA-ordering hazard)
//     K-tiles 4-6: A = PE fragments computed per-lane in registers
//   Epilogue: fused bias/lrelu/residual, direct stores (64B segments).
// Independent waves overlap each other's load stalls (no lockstep barriers —
// the structural fix for the 10-14% MfmaUtil / all-idle signature of R0-R4).
// ---------------------------------------------------------------------------
__global__ __launch_bounds__(512, 2) void gemm_stream(
    const float* __restrict__ X,     // [65536, 256] f32
    const float* __restrict__ PC,    // [65536, 3]
    const float* __restrict__ lff_w, // [96,3]
    const float* __restrict__ lff_b, // [96]
    const float* __restrict__ cpeT,  // [3,90,96]
    const __bf16* __restrict__ Bw,   // [1024, 448] bf16
    const float* __restrict__ bias,  // [1024]
    float* __restrict__ out)         // x_up part of d_out
{
    __shared__ __attribute__((aligned(16))) __bf16 Bs[64 * 448];  // 56 KB

    const int tid  = threadIdx.x;
    const int wave = tid >> 6;
    const int lane = tid & 63;
    const int quad = lane >> 4;
    const int l16  = lane & 15;

    // XCD-aware mapping: xcd = bx&7 owns 32 contiguous M-groups; within an
    // XCD the 16 N-tiles of one M-group are dispatched consecutively
    // (A-rows and residual-X stay L2-hot across the 16 B-panels).
    const unsigned bx = blockIdx.x;           // [0, 4096)
    const unsigned q  = bx >> 3;              // [0, 512)
    const int bm = (int)(((bx & 7u) * 32u + (q >> 4)) * 256u);  // 256 M-groups
    const int bn = (int)((q & 15u) * 64u);                       // 16 N-tiles

    // ---- stage B panel once: 64 rows x 448 k, pre-swizzled source ----
    // LDS chunk (r, c) holds global chunk (c & ~7) | ((c&7)^(r&7)) of row r;
    // reads below apply the same involution -> conflict-free ds_read_b128.
    #pragma unroll
    for (int qq = 0; qq < 7; ++qq) {
        const int idx = qq * 512 + tid;       // [0, 3584) 16B chunks
        const int r   = idx / 56;
        const int c   = idx % 56;
        const int cs  = (c & 7) ^ (r & 7);
        g2lds16(Bw + (size_t)(bn + r) * K_TOTAL + (c >> 3) * 64 + cs * 8,
                Bs + (size_t)(qq * 512 + wave * 64) * 8);
    }

    const int m0 = bm + wave * 32 + l16;      // lane's A-row for i=0

    // hoist pc for the lane's two rows (quads share l16 -> broadcast loads)
    float pcr[2][3];
    #pragma unroll
    for (int i = 0; i < 2; ++i) {
        const float* p = PC + (size_t)(m0 + i * 16) * 3;
        pcr[i][0] = p[0]; pcr[i][1] = p[1]; pcr[i][2] = p[2];
    }

    float4 xa[2][8];   // X prefetch, tile-parity sets (indices const post-unroll)
    auto loadX = [&](float4* x8, int t) {
        const int kt = t * 64;
        #pragma unroll
        for (int i = 0; i < 2; ++i)
            #pragma unroll
            for (int s = 0; s < 2; ++s) {
                const float* src = X + (size_t)(m0 + i * 16) * 256
                                     + kt + s * 32 + quad * 8;
                x8[(i * 2 + s) * 2]     = *(const float4*)src;
                x8[(i * 2 + s) * 2 + 1] = *(const float4*)(src + 4);
            }
    };

    loadX(xa[0], 0);
    __syncthreads();   // B panel visible (drains vmcnt incl. LDS-DMA). ONLY sync.

    floatx4 acc[2][4];
    #pragma unroll
    for (int i = 0; i < 2; ++i)
        #pragma unroll
        for (int j = 0; j < 4; ++j)
            acc[i][j] = (floatx4){0.f, 0.f, 0.f, 0.f};

    #pragma unroll
    for (int t = 0; t < 7; ++t) {
        // prefetch next X tile (tiles 1..3) while computing this one
        if (t < 3) loadX(xa[(t + 1) & 1], t + 1);

        // build A fragments af[i*2+s] for this K-tile
        bf16x8 af[4];
        if (t < 4) {
            const float4* x8 = xa[t & 1];
            #pragma unroll
            for (int f = 0; f < 4; ++f) {
                float4 a = x8[f * 2], b = x8[f * 2 + 1];
                bf16x8 o = { (__bf16)a.x, (__bf16)a.y, (__bf16)a.z, (__bf16)a.w,
                             (__bf16)b.x, (__bf16)b.y, (__bf16)b.z, (__bf16)b.w };
                af[f] = o;
            }
        } else if (t == 4) {
            af[0] = pe_frag<0>  (quad, pcr[0][0], pcr[0][1], pcr[0][2], lff_w, lff_b, cpeT);
            af[1] = pe_frag<32> (quad, pcr[0][0], pcr[0][1], pcr[0][2], lff_w, lff_b, cpeT);
            af[2] = pe_frag<0>  (quad, pcr[1][0], pcr[1][1], pcr[1][2], lff_w, lff_b, cpeT);
            af[3] = pe_frag<32> (quad, pcr[1][0], pcr[1][1], pcr[1][2], lff_w, lff_b, cpeT);
        } else if (t == 5) {
            af[0] = pe_frag<64> (quad, pcr[0][0], pcr[0][1], pcr[0][2], lff_w, lff_b, cpeT);
            af[1] = pe_frag<96> (quad, pcr[0][0], pcr[0][1], pcr[0][2], lff_w, lff_b, cpeT);
            af[2] = pe_frag<64> (quad, pcr[1][0], pcr[1][1], pcr[1][2], lff_w, lff_b, cpeT);
            af[3] = pe_frag<96> (quad, pcr[1][0], pcr[1][1], pcr[1][2], lff_w, lff_b, cpeT);
        } else {
            af[0] = pe_frag<128>(quad, pcr[0][0], pcr[0][1], pcr[0][2], lff_w, lff_b, cpeT);
            af[1] = pe_frag<160>(quad, pcr[0][0], pcr[0][1], pcr[0][2], lff_w, lff_b, cpeT);
            af[2] = pe_frag<128>(quad, pcr[1][0], pcr[1][1], pcr[1][2], lff_w, lff_b, cpeT);
            af[3] = pe_frag<160>(quad, pcr[1][0], pcr[1][1], pcr[1][2], lff_w, lff_b, cpeT);
        }

        // MFMA against LDS-resident B (read-only -> no hazards, no barriers)
        #pragma unroll
        for (int s = 0; s < 2; ++s) {
            bf16x8 bfr[4];
            #pragma unroll
            for (int j = 0; j < 4; ++j) {
                const int row = j * 16 + l16;
                bfr[j] = *(const bf16x8*)(Bs + (size_t)row * 448 + t * 64
                                          + ((s * 4 + quad) ^ (row & 7)) * 8);
            }
            __builtin_amdgcn_s_setprio(1);
            #pragma unroll
            for (int i = 0; i < 2; ++i)
                #pragma unroll
                for (int j = 0; j < 4; ++j)
                    acc[i][j] = __builtin_amdgcn_mfma_f32_16x16x32_bf16(
                        af[i * 2 + s], bfr[j], acc[i][j], 0, 0, 0);
            __builtin_amdgcn_s_setprio(0);
        }
    }

    // ---- fused epilogue: bias/lrelu/residual, direct stores ----
    const float gain = 0.047245559126153576f;     // 1/sqrt(448)
    const float inv_sqrt2 = 0.70710678118654752f;
    #pragma unroll
    for (int j = 0; j < 4; ++j) {
        const int n = bn + j * 16 + l16;
        const float bs = bias[n];
        const int u = n >> 8;
        const int o = n & 255;
        #pragma unroll
        for (int i = 0; i < 2; ++i)
            #pragma unroll
            for (int r = 0; r < 4; ++r) {
                const int m = bm + wave * 32 + i * 16 + quad * 4 + r;
                float y = fmaf(acc[i][j][r], gain, bs);
                float act = (y >= 0.f) ? y : 0.2f * y;   // lrelu*sqrt2 /sqrt2 == 1
                float res = X[(size_t)m * 256 + o];      // L2-warm (A-stream)
                out[((size_t)(m * 4 + u)) * 256 + o] = fmaf(res, inv_sqrt2, act);
            }
    }
}

// ---------------------------------------------------------------------------
extern "C" void kernel_launch(void* const* d_in, const int* in_sizes, int n_in,
                              void* d_out, int out_size, void* d_ws, size_t ws_size,
                              hipStream_t stream) {
    const float* X      = (const float*)d_in[0];  // [8,8192,256]
    const float* pc     = (const float*)d_in[1];  // [8,8192,3]
    const float* lff_w  = (const float*)d_in[2];  // [96,3]
    const float* lff_b  = (const float*)d_in[3];  // [96]
    const float* cpe    = (const float*)d_in[4];  // [3,96,90]
    const float* sub_w  = (const float*)d_in[5];  // [1024,448]
    const float* sub_b  = (const float*)d_in[6];  // [1024]

    float* out    = (float*)d_out;                       // x_up: 67108864 floats
    float* out_pc = out + (size_t)M_TOTAL * 4 * 256;     // pc_up: 786432 floats

    // workspace: sub_w bf16 [1024,448], cpeT f32 [3,90,96]
    __bf16* wb   = (__bf16*)d_ws;
    float*  cpeT = (float*)((char*)d_ws + (size_t)N_TOTAL * K_TOTAL * 2);

    convert_w    <<<448,  256, 0, stream>>>(sub_w, wb);
    transpose_cpe<<<102,  256, 0, stream>>>(cpe, cpeT);
    pc_up_kernel <<<3072, 256, 0, stream>>>(pc, out_pc);
    gemm_stream  <<<4096, 512, 0, stream>>>(X, pc, lff_w, lff_b, cpeT, wb, sub_b, out);
}

// Round 7
// 431.784 us; speedup vs baseline: 1.6393x; 1.6393x over previous
//
#include <hip/hip_runtime.h>
#include <hip/hip_bf16.h>

// Problem constants (B=8, L=8192, C=256, PE=96, R=90, UP=4, OUT=256)
#define M_TOTAL 65536   // B*L
#define N_TOTAL 1024    // OUT*UP
#define K_TOTAL 448     // C + 2*PE
#define R_PE    90

typedef __bf16 bf16x8 __attribute__((ext_vector_type(8)));
typedef __bf16 bf16x4 __attribute__((ext_vector_type(4)));
typedef float  floatx4 __attribute__((ext_vector_type(4)));

// ---------------------------------------------------------------------------
// async global->LDS, 16B per lane. LDS dest = wave-uniform base + lane*16.
// ---------------------------------------------------------------------------
__device__ __forceinline__ void g2lds16(const void* g, void* l) {
    __builtin_amdgcn_global_load_lds(
        (const __attribute__((address_space(1))) void*)g,
        (__attribute__((address_space(3))) void*)l,
        16, 0, 0);
}

// ---------------------------------------------------------------------------
// cpe [3][96][90] -> cpeT [3][90][96] so the per-row d-gather is coalesced.
// ---------------------------------------------------------------------------
__global__ __launch_bounds__(256) void transpose_cpe(
    const float* __restrict__ cpe, float* __restrict__ cpeT)
{
    int i = blockIdx.x * 256 + threadIdx.x;
    if (i < 3 * 96 * R_PE) {
        int c = i / (96 * R_PE);
        int rem = i % (96 * R_PE);
        int d = rem / R_PE;
        int r = rem % R_PE;
        cpeT[((size_t)c * R_PE + r) * 96 + d] = cpe[i];
    }
}

// ---------------------------------------------------------------------------
// Stage 1: x_pe[m, 0:448] = [bf16(x[m]), sin(LFF(pc[m])), constPE(pc[m])]
// One row per WAVE (R1-proven): pc lane-uniform; X copy 64xfloat4; LFF
// weights hoisted; cpeT gathers coalesced.
// ---------------------------------------------------------------------------
__global__ __launch_bounds__(256) void build_xpe(
    const float* __restrict__ X,      // [65536, 256]
    const float* __restrict__ pc,     // [65536, 3]
    const float* __restrict__ lff_w,  // [96, 3]
    const float* __restrict__ lff_b,  // [96]
    const float* __restrict__ cpeT,   // [3, 90, 96] (transposed)
    __bf16* __restrict__ xpe)         // [65536, 448]
{
    const int wave = threadIdx.x >> 6;
    const int lane = threadIdx.x & 63;

    const float w00 = lff_w[lane * 3 + 0];
    const float w01 = lff_w[lane * 3 + 1];
    const float w02 = lff_w[lane * 3 + 2];
    const float bb0 = lff_b[lane];
    float w10 = 0.f, w11 = 0.f, w12 = 0.f, bb1 = 0.f;
    if (lane < 32) {
        w10 = lff_w[(64 + lane) * 3 + 0];
        w11 = lff_w[(64 + lane) * 3 + 1];
        w12 = lff_w[(64 + lane) * 3 + 2];
        bb1 = lff_b[64 + lane];
    }

    for (int m = blockIdx.x * 4 + wave; m < M_TOTAL; m += gridDim.x * 4) {
        const float p0 = pc[m * 3 + 0];
        const float p1 = pc[m * 3 + 1];
        const float p2 = pc[m * 3 + 2];
        __bf16* row = xpe + (size_t)m * K_TOTAL;

        float4 v = ((const float4*)(X + (size_t)m * 256))[lane];
        bf16x4 xo = { (__bf16)v.x, (__bf16)v.y, (__bf16)v.z, (__bf16)v.w };
        *(bf16x4*)(row + lane * 4) = xo;

        float a0 = fmaf(p2, w02, fmaf(p1, w01, fmaf(p0, w00, bb0)));
        row[256 + lane] = (__bf16)__sinf(a0);
        if (lane < 32) {
            float a1 = fmaf(p2, w12, fmaf(p1, w11, fmaf(p0, w10, bb1)));
            row[256 + 64 + lane] = (__bf16)__sinf(a1);
        }

        const float pch[3] = { p0, p1, p2 };
        const float* tab0[3];
        const float* tab1[3];
        float m0[3], m1[3];
        #pragma unroll
        for (int c = 0; c < 3; ++c) {
            float ix = (pch[c] + 1.f) * 45.f - 0.5f;   // ((p+1)*R-1)*0.5
            float fl = floorf(ix);
            float w  = ix - fl;
            int   i0 = (int)fl;
            bool  ok0 = (i0 >= 0) && (i0 < R_PE);
            bool  ok1 = (i0 + 1 >= 0) && (i0 + 1 < R_PE);
            int   c0 = ok0 ? i0 : 0;
            int   c1 = ok1 ? i0 + 1 : 0;
            tab0[c] = cpeT + ((size_t)c * R_PE + c0) * 96;
            tab1[c] = cpeT + ((size_t)c * R_PE + c1) * 96;
            m0[c] = ok0 ? (1.f - w) : 0.f;
            m1[c] = ok1 ? w : 0.f;
        }
        float acc0 = 0.f;
        #pragma unroll
        for (int c = 0; c < 3; ++c)
            acc0 += m0[c] * tab0[c][lane] + m1[c] * tab1[c][lane];
        row[352 + lane] = (__bf16)(acc0 * 0.57735026918962576f);  // 1/sqrt(3)
        if (lane < 32) {
            float acc1 = 0.f;
            #pragma unroll
            for (int c = 0; c < 3; ++c)
                acc1 += m0[c] * tab0[c][64 + lane] + m1[c] * tab1[c][64 + lane];
            row[352 + 64 + lane] = (__bf16)(acc1 * 0.57735026918962576f);
        }
    }
}

// ---------------------------------------------------------------------------
// sub_w [1024,448] f32 -> bf16 (already B^T layout: N-major, K-contiguous)
// ---------------------------------------------------------------------------
__global__ __launch_bounds__(256) void convert_w(
    const float* __restrict__ w, __bf16* __restrict__ wb)
{
    int i = (blockIdx.x * 256 + threadIdx.x) * 4;
    if (i < N_TOTAL * K_TOTAL) {
        float4 v = *(const float4*)(w + i);
        bf16x4 o = { (__bf16)v.x, (__bf16)v.y, (__bf16)v.z, (__bf16)v.w };
        *(bf16x4*)(wb + i) = o;
    }
}

// ---------------------------------------------------------------------------
// pc_up: repeat_interleave(pc, 4, axis=1)
// ---------------------------------------------------------------------------
__global__ __launch_bounds__(256) void pc_up_kernel(
    const float* __restrict__ pc, float* __restrict__ out2)
{
    int e = blockIdx.x * 256 + threadIdx.x;
    if (e < M_TOTAL * 12) {
        int m = e / 12;
        int j = e % 3;
        out2[e] = pc[m * 3 + j];
    }
}

// ---------------------------------------------------------------------------
// GEMM: C[m,n] = sum_k xpe[m,k] * sub_w[n,k], fused subpixel epilogue.
// R6 change vs R1: tile 128x128 -> 128x64 (BK=64, 4 waves, wave = 32 rows x
// 64 cols). acc 64->32 regs (unified-file pressure was capping residency at
// 2 blocks/CU), LDS 64->48 KB -> 3 blocks/CU. Sync scheme is R1's PROVEN
// drain pipeline: issue next-tile DMA early, compute, vmcnt(0)+barrier.
// Both-side XOR swizzle (pre-swizzled DMA source + swizzled ds_read).
// ---------------------------------------------------------------------------
__global__ __launch_bounds__(256) void gemm_kernel(
    const __bf16* __restrict__ A,    // [65536, 448] bf16 (x_pe)
    const __bf16* __restrict__ Bw,   // [1024, 448] bf16 (sub_w^T-major)
    const float* __restrict__ bias,  // [1024]
    const float* __restrict__ X,     // [65536, 256] f32 residual
    float* __restrict__ out)         // x_up part of d_out
{
    __shared__ __attribute__((aligned(16))) __bf16 As[2][128 * 64];  // 2 x 16 KB
    __shared__ __attribute__((aligned(16))) __bf16 Bs[2][64 * 64];   // 2 x 8 KB

    const int tid  = threadIdx.x;
    const int wave = tid >> 6;
    const int lane = tid & 63;
    const int quad = lane >> 4;
    const int l16  = lane & 15;
    const int wm   = wave * 32;      // wave's row origin in the 128-row tile

    // XCD-aware swizzle, 8192 blocks: each XCD owns 64 contiguous M-tiles;
    // the 16 N-blocks of one M-tile dispatch consecutively (A-tile + residual
    // X stay L2-hot across them).
    const unsigned bx = blockIdx.x;           // [0, 8192)
    const unsigned q  = bx >> 3;              // [0, 1024)
    const int bm = (int)(((bx & 7u) * 64u + (q >> 4)) * 128u);  // 512 M-tiles
    const int bn = (int)((q & 15u) * 64u);                      // 16 N-tiles

    floatx4 acc[2][4];
    #pragma unroll
    for (int i = 0; i < 2; ++i)
        #pragma unroll
        for (int j = 0; j < 4; ++j)
            acc[i][j] = (floatx4){0.f, 0.f, 0.f, 0.f};

    auto stage = [&](int buf, int tt) {       // 4 A-chunks + 2 B-chunks / thread
        const int kt = tt * 64;
        #pragma unroll
        for (int s = 0; s < 4; ++s) {
            const int idx = s * 256 + tid;          // A chunk id, [0,1024)
            const int r   = idx >> 3;               // tile row [0,128)
            const int cs  = (idx & 7) ^ (r & 7);    // pre-swizzled source chunk
            g2lds16(A + (size_t)(bm + r) * K_TOTAL + kt + cs * 8,
                    &As[buf][(size_t)(s * 256 + wave * 64) * 8]);
        }
        #pragma unroll
        for (int s = 0; s < 2; ++s) {
            const int idx = s * 256 + tid;          // B chunk id, [0,512)
            const int r   = idx >> 3;               // tile row [0,64)
            const int cs  = (idx & 7) ^ (r & 7);
            g2lds16(Bw + (size_t)(bn + r) * K_TOTAL + kt + cs * 8,
                    &Bs[buf][(size_t)(s * 256 + wave * 64) * 8]);
        }
    };

    // prologue: stage tile 0, drain, publish
    stage(0, 0);
    asm volatile("s_waitcnt vmcnt(0)" ::: "memory");
    __builtin_amdgcn_s_barrier();

    #pragma unroll
    for (int t = 0; t < 7; ++t) {
        const int cur = t & 1;
        if (t < 6) stage(cur ^ 1, t + 1);   // issue next-tile DMA (overlaps)

        #pragma unroll
        for (int s = 0; s < 2; ++s) {
            bf16x8 af[2], bfr[4];
            #pragma unroll
            for (int i = 0; i < 2; ++i) {
                const int row = wm + i * 16 + l16;
                const int ch  = (s * 4 + quad) ^ (row & 7);   // read-side swizzle
                af[i] = *(const bf16x8*)(&As[cur][row * 64 + ch * 8]);
            }
            #pragma unroll
            for (int j = 0; j < 4; ++j) {
                const int row = j * 16 + l16;
                const int ch  = (s * 4 + quad) ^ (row & 7);
                bfr[j] = *(const bf16x8*)(&Bs[cur][row * 64 + ch * 8]);
            }
            __builtin_amdgcn_s_setprio(1);
            #pragma unroll
            for (int i = 0; i < 2; ++i)
                #pragma unroll
                for (int j = 0; j < 4; ++j)
                    acc[i][j] = __builtin_amdgcn_mfma_f32_16x16x32_bf16(
                        af[i], bfr[j], acc[i][j], 0, 0, 0);
            __builtin_amdgcn_s_setprio(0);
        }

        // drain next-tile DMA (latency hidden under compute), publish, swap
        if (t < 6) {
            asm volatile("s_waitcnt vmcnt(0) lgkmcnt(0)" ::: "memory");
            __builtin_amdgcn_s_barrier();
        }
    }

    // ---- fused epilogue (direct stores; R4 showed LDS round-trip no better)
    const float gain = 0.047245559126153576f;     // 1/sqrt(448)
    const float inv_sqrt2 = 0.70710678118654752f;
    const int u     = bn >> 8;
    const int obase = bn & 255;
    #pragma unroll
    for (int j = 0; j < 4; ++j) {
        const int n = bn + j * 16 + l16;
        const float bs = bias[n];
        const int o = obase + j * 16 + l16;
        #pragma unroll
        for (int i = 0; i < 2; ++i) {
            #pragma unroll
            for (int r = 0; r < 4; ++r) {
                const int m = bm + wm + i * 16 + quad * 4 + r;
                float y = fmaf(acc[i][j][r], gain, bs);
                float act = (y >= 0.f) ? y : 0.2f * y;   // lrelu*sqrt2 /sqrt2 == 1
                float res = X[(size_t)m * 256 + o];      // L2-warm via XCD swizzle
                out[((size_t)(m * 4 + u)) * 256 + o] = fmaf(res, inv_sqrt2, act);
            }
        }
    }
}

// ---------------------------------------------------------------------------
extern "C" void kernel_launch(void* const* d_in, const int* in_sizes, int n_in,
                              void* d_out, int out_size, void* d_ws, size_t ws_size,
                              hipStream_t stream) {
    const float* X      = (const float*)d_in[0];  // [8,8192,256]
    const float* pc     = (const float*)d_in[1];  // [8,8192,3]
    const float* lff_w  = (const float*)d_in[2];  // [96,3]
    const float* lff_b  = (const float*)d_in[3];  // [96]
    const float* cpe    = (const float*)d_in[4];  // [3,96,90]
    const float* sub_w  = (const float*)d_in[5];  // [1024,448]
    const float* sub_b  = (const float*)d_in[6];  // [1024]

    float* out    = (float*)d_out;                       // x_up: 67108864 floats
    float* out_pc = out + (size_t)M_TOTAL * 4 * 256;     // pc_up: 786432 floats

    // workspace: x_pe bf16 [65536,448], sub_w bf16 [1024,448], cpeT f32 [3,90,96]
    __bf16* xpe  = (__bf16*)d_ws;
    __bf16* wb   = (__bf16*)((char*)d_ws + (size_t)M_TOTAL * K_TOTAL * 2);
    float*  cpeT = (float*)((char*)d_ws + (size_t)M_TOTAL * K_TOTAL * 2
                                        + (size_t)N_TOTAL * K_TOTAL * 2);

    convert_w    <<<448,  256, 0, stream>>>(sub_w, wb);
    pc_up_kernel <<<3072, 256, 0, stream>>>(pc, out_pc);
    transpose_cpe<<<102,  256, 0, stream>>>(cpe, cpeT);
    build_xpe    <<<4096, 256, 0, stream>>>(X, pc, lff_w, lff_b, cpeT, xpe);
    gemm_kernel  <<<8192, 256, 0, stream>>>(xpe, wb, sub_b, X, out);
}